// Round 2
// baseline (935.486 us; speedup 1.0000x reference)
//
#include <hip/hip_runtime.h>

#define H   1024
#define S   64
#define V   32000
#define EMB 1088
#define GIN 2112

// workspace layout (float32 elements)
// [0..16)   : grid-barrier counters (memset to 0 by kernel_launch each call)
#define WS_GI   2112     // 3072
#define WS_GH   5184     // 3072
#define WS_JOIN 8256     // 2048  : [h_new | attn_context]
#define WS_SG   10304    // 32000 : score_g   (contiguous with WS_SC!)
#define WS_SC   42304    // 64    : score_c (reduced)
#define WS_SCP  42376    // 2048  : score_c partials [s][g] (64 x 32)

#define NBLK 512

typedef unsigned short ushort_t;
typedef unsigned int   uint_t;

__device__ __forceinline__ float b2f(ushort_t u) {
  union { uint_t i; float f; } v; v.i = ((uint_t)u) << 16; return v.f;
}
__device__ __forceinline__ float bl(uint_t u) {
  union { uint_t i; float f; } v; v.i = u << 16; return v.f;
}
__device__ __forceinline__ float bh(uint_t u) {
  union { uint_t i; float f; } v; v.i = u & 0xffff0000u; return v.f;
}
__device__ __forceinline__ ushort_t f2b(float f) {
  union { float f; uint_t u; } v; v.f = f;
  uint_t u = v.u;
  u += 0x7fffu + ((u >> 16) & 1u);   // RNE
  return (ushort_t)(u >> 16);
}

struct L8 { float v[8]; };

template<bool B>
__device__ __forceinline__ L8 load8(const void* base, size_t idx) {
  L8 r;
  if (B) {
    uint4 pk = *(const uint4*)((const ushort_t*)base + idx);
    r.v[0]=bl(pk.x); r.v[1]=bh(pk.x); r.v[2]=bl(pk.y); r.v[3]=bh(pk.y);
    r.v[4]=bl(pk.z); r.v[5]=bh(pk.z); r.v[6]=bl(pk.w); r.v[7]=bh(pk.w);
  } else {
    const float4* p = (const float4*)((const float*)base + idx);
    float4 a = p[0], b = p[1];
    r.v[0]=a.x; r.v[1]=a.y; r.v[2]=a.z; r.v[3]=a.w;
    r.v[4]=b.x; r.v[5]=b.y; r.v[6]=b.z; r.v[7]=b.w;
  }
  return r;
}
template<bool B>
__device__ __forceinline__ float ld1(const void* base, size_t idx) {
  return B ? b2f(((const ushort_t*)base)[idx]) : ((const float*)base)[idx];
}
template<bool B>
__device__ __forceinline__ void st1(void* base, size_t idx, float f) {
  if (B) ((ushort_t*)base)[idx] = f2b(f);
  else   ((float*)base)[idx] = f;
}
__device__ __forceinline__ float dot8f(L8 w, const float* xp) {
  const float4* p = (const float4*)xp;
  float4 a = p[0], b = p[1];
  return w.v[0]*a.x + w.v[1]*a.y + w.v[2]*a.z + w.v[3]*a.w
       + w.v[4]*b.x + w.v[5]*b.y + w.v[6]*b.z + w.v[7]*b.w;
}

// ---- custom grid barrier (device-scope acq/rel; does NOT rely on
// hipLaunchCooperativeKernel, which silently no-ops under graph capture).
// Writer side: compiler drains vmcnt before s_barrier, then the acq_rel
// fetch_add (agent scope) writes back the XCD L2. Reader side: the acquire
// spin-load invalidates L1/L2; __syncthreads orders all other lanes' loads
// after it (same CU -> same L1).
__device__ __forceinline__ void gridbar(int* c) {
  __threadfence();
  __syncthreads();
  if (threadIdx.x == 0) {
    __hip_atomic_fetch_add(c, 1, __ATOMIC_ACQ_REL, __HIP_MEMORY_SCOPE_AGENT);
    int it = 0;
    while (__hip_atomic_load(c, __ATOMIC_ACQUIRE, __HIP_MEMORY_SCOPE_AGENT)
               < NBLK && it < 4000000) {
      __builtin_amdgcn_s_sleep(2);
      ++it;
    }
  }
  __syncthreads();
}

struct Sm {
  float s_x[GIN];
  float s_h[H];
  float s_loc[S];
  float s_part[8];
  float s_hn[H];
  float s_sc[S];
  float s_w[S];
  float s_j[2 * H];
  float red[4];
  float s_pc[S];
  int   s_src[S];
  int   s_di;
};

// One kernel: 512 blocks x 256 threads, 3 grid barriers.
// Phase A: blocks 0..255 GRU-gates GEMV (3 rows/wave), blocks 256..511
//          copy-attn score_c partials.
// Phase M: block 0 = h_new + attn scores + softmax + context,
//          block 1 = score_c reduce, blocks 2..5 = h_new -> ws/d_out.
// Phase D: all blocks: score_g GEMV (16 consecutive rows per wave).
// Phase EF: blocks 0..124: per-block redundant LSE (L2-resident, 128KB) +
//           final scatter/write.
template<bool B>
__device__ void body(const int* word_input, const void* prev_context,
                     const void* ph, const void* enc, const int* sources,
                     const void* emb_table, const void* Wih, const void* Whh,
                     const void* bih, const void* bhh, const void* copy_W,
                     const void* copy_b, const void* gen_W, const void* gen_b,
                     float* ws, void* d_out, Sm* sm, int di) {
  int tid  = threadIdx.x;
  int bid  = blockIdx.x;
  int wave = tid >> 6, lane = tid & 63;
  int* bar = (int*)ws;

  // ===================== phase A =====================
  if (bid < 256) {
    // ---- GRU gates (3072 rows over 1024 waves, 3 rows each)
    if (tid < 64) {
      bool m = (sources[tid] == di);
      unsigned long long bal = __ballot(m);
      int c = __popcll(bal);
      float inv = (c > 0) ? (1.0f / sqrtf((float)c)) : 0.0f;
      sm->s_loc[tid] = m ? inv : 0.0f;
    }
    __syncthreads();
    int w = word_input[0];
    size_t eoff = (size_t)w * EMB;
    for (int i = tid; i < GIN; i += 256) {
      float v;
      if (i < S)        v = sm->s_loc[i];
      else if (i < EMB) v = ld1<B>(emb_table, eoff + i);
      else              v = ld1<B>(prev_context, i - EMB);
      sm->s_x[i] = v;
    }
    for (int i = tid; i < H; i += 256) sm->s_h[i] = ld1<B>(ph, i);
    __syncthreads();
    int wg = bid * 4 + wave;            // 0..1023
#pragma unroll
    for (int rr = 0; rr < 3; ++rr) {
      int r = wg * 3 + rr;              // 0..3071
      size_t ro = (size_t)r * GIN;
      float sum1 = 0.f;
#pragma unroll
      for (int it = 0; it < 4; ++it) {
        int j = it * 512 + lane * 8;
        sum1 += dot8f(load8<B>(Wih, ro + j), sm->s_x + j);
      }
      sum1 += ld1<B>(Wih, ro + 2048 + lane) * sm->s_x[2048 + lane];
      size_t ho = (size_t)r * H;
      float sum2 = 0.f;
#pragma unroll
      for (int it = 0; it < 2; ++it) {
        int j = it * 512 + lane * 8;
        sum2 += dot8f(load8<B>(Whh, ho + j), sm->s_h + j);
      }
#pragma unroll
      for (int off = 32; off; off >>= 1) {
        sum1 += __shfl_down(sum1, off);
        sum2 += __shfl_down(sum2, off);
      }
      if (lane == 0) {
        ws[WS_GI + r] = sum1 + ld1<B>(bih, r);
        ws[WS_GH + r] = sum2 + ld1<B>(bhh, r);
      }
    }
  } else {
    // ---- copy-attn score_c partials (unit b = bid-256)
    int b  = bid - 256;                 // 0..255
    int sg = b >> 5;                    // 0..7
    int s0 = sg * 8;
    int g  = b & 31;                    // 0..31
    int hh0 = (g * 4 + wave) * 8;       // 0..1016
    if (tid < 8) sm->s_part[tid] = 0.f;
    __syncthreads();

    float acc[64];
#pragma unroll
    for (int k = 0; k < 64; ++k) acc[k] = 0.f;
#pragma unroll
    for (int it = 0; it < 2; ++it) {
      int j = it * 512 + lane * 8;
      L8 e[8];
#pragma unroll
      for (int si = 0; si < 8; ++si)
        e[si] = load8<B>(enc, (size_t)(s0 + si) * H + j);
#pragma unroll
      for (int hi = 0; hi < 8; ++hi) {
        L8 wv = load8<B>(copy_W, (size_t)(hh0 + hi) * H + j);
#pragma unroll
        for (int si = 0; si < 8; ++si) {
          float t = 0.f;
#pragma unroll
          for (int q = 0; q < 8; ++q) t += wv.v[q] * e[si].v[q];
          acc[si * 8 + hi] += t;
        }
      }
    }
    // butterfly transpose-reduce: lane L ends with full sum of acc[L]
#pragma unroll
    for (int st = 5; st >= 0; --st) {
      int n = 1 << st;
      bool hi = (lane & n) != 0;
#pragma unroll
      for (int i = 0; i < 32; ++i) {
        if (i < n) {
          float keep = hi ? acc[i + n] : acc[i];
          float send = hi ? acc[i] : acc[i + n];
          acc[i] = keep + __shfl_xor(send, n);
        }
      }
    }
    int hi_idx = lane & 7;
    int si = lane >> 3;
    int hh = hh0 + hi_idx;
    float val = tanhf(acc[0] + ld1<B>(copy_b, hh)) * ld1<B>(ph, hh);
    val += __shfl_xor(val, 1);
    val += __shfl_xor(val, 2);
    val += __shfl_xor(val, 4);
    if (hi_idx == 0) atomicAdd(&sm->s_part[si], val);
    __syncthreads();
    if (tid < 8)
      ws[WS_SCP + (size_t)(s0 + tid) * 32 + g] = sm->s_part[tid];
  }
  gridbar(bar + 0);

  // ===================== phase M =====================
  if (bid == 0) {
    // full h_new into LDS
    for (int i = tid; i < H; i += 256) {
      float gr = ws[WS_GI + i]     + ws[WS_GH + i];
      float gz = ws[WS_GI + H + i] + ws[WS_GH + H + i];
      float r  = 1.f / (1.f + expf(-gr));
      float z  = 1.f / (1.f + expf(-gz));
      float n  = tanhf(ws[WS_GI + 2*H + i] + r * ws[WS_GH + 2*H + i]);
      float h  = ld1<B>(ph, i);
      sm->s_hn[i] = (1.f - z) * n + z * h;
    }
    __syncthreads();
    // 64 attention scores: 4 waves x 16 rows
#pragma unroll 2
    for (int q = 0; q < 16; ++q) {
      int s = wave * 16 + q;
      size_t eo = (size_t)s * H;
      float sum = 0.f;
#pragma unroll
      for (int it = 0; it < 2; ++it) {
        int j = it * 512 + lane * 8;
        sum += dot8f(load8<B>(enc, eo + j), sm->s_hn + j);
      }
#pragma unroll
      for (int off = 32; off; off >>= 1) sum += __shfl_down(sum, off);
      if (lane == 0) sm->s_sc[s] = sum;
    }
    __syncthreads();
    // softmax over 64 scores (wave 0)
    if (tid < 64) {
      float vv = sm->s_sc[tid];
      float m = vv;
#pragma unroll
      for (int off = 32; off; off >>= 1) m = fmaxf(m, __shfl_xor(m, off));
      float e = expf(vv - m);
      float smx = e;
#pragma unroll
      for (int off = 32; off; off >>= 1) smx += __shfl_xor(smx, off);
      float wgt = e / smx;
      sm->s_w[tid] = wgt;
      st1<B>(d_out, V + 2*H + tid, wgt);      // attn_weights
    }
    __syncthreads();
    // context = attn_weights @ enc
    for (int i = tid; i < H; i += 256) {
      float acc = 0.f;
#pragma unroll 4
      for (int s = 0; s < S; ++s)
        acc += sm->s_w[s] * ld1<B>(enc, (size_t)s * H + i);
      ws[WS_JOIN + H + i] = acc;
      st1<B>(d_out, V + i, acc);              // attn_context
    }
  } else if (bid == 1) {
    // reduce score_c partials
    if (tid < 64) {
      float sc = 0.f;
#pragma unroll
      for (int g2 = 0; g2 < 32; ++g2) sc += ws[WS_SCP + (size_t)tid * 32 + g2];
      ws[WS_SC + tid] = sc;
    }
  } else if (bid < 6) {
    // h_new -> joined[0:H] + d_out (elementwise, 4 blocks x 256 dims)
    int i = (bid - 2) * 256 + tid;
    float gr = ws[WS_GI + i]     + ws[WS_GH + i];
    float gz = ws[WS_GI + H + i] + ws[WS_GH + H + i];
    float r  = 1.f / (1.f + expf(-gr));
    float z  = 1.f / (1.f + expf(-gz));
    float n  = tanhf(ws[WS_GI + 2*H + i] + r * ws[WS_GH + 2*H + i]);
    float h  = ld1<B>(ph, i);
    float hn = (1.f - z) * n + z * h;
    ws[WS_JOIN + i] = hn;
    st1<B>(d_out, V + H + i, hn);             // current_hidden
  }
  gridbar(bar + 1);

  // ===================== phase D: score_g =====================
  for (int i = tid; i < 2 * H; i += 256) sm->s_j[i] = ws[WS_JOIN + i];
  __syncthreads();
  {
    int gw = bid * 4 + wave;                  // 0..2047
    int base = gw * 16;                       // 16 consecutive rows per wave
#pragma unroll 2
    for (int q = 0; q < 16; ++q) {
      int v = base + q;
      if (v < V) {
        size_t ro = (size_t)v * (2 * H);
        float sum = 0.f;
#pragma unroll
        for (int it = 0; it < 4; ++it) {
          int j = it * 512 + lane * 8;
          sum += dot8f(load8<B>(gen_W, ro + j), sm->s_j + j);
        }
#pragma unroll
        for (int off = 32; off; off >>= 1) sum += __shfl_down(sum, off);
        if (lane == 0) ws[WS_SG + v] = sum + ld1<B>(gen_b, v);
      }
    }
  }
  gridbar(bar + 2);

  // ===================== phase E/F: per-block LSE + final =====================
  if (bid < 125) {
    // SG(32000) || SC(64) are contiguous: 8016 float4
    const float4* sc4 = (const float4*)(ws + WS_SG);
    float m = -3.0e38f;
    for (int i = tid; i < 8016; i += 256) {
      float4 v = sc4[i];
      m = fmaxf(m, fmaxf(fmaxf(v.x, v.y), fmaxf(v.z, v.w)));
    }
#pragma unroll
    for (int off = 32; off; off >>= 1) m = fmaxf(m, __shfl_xor(m, off));
    if (lane == 0) sm->red[wave] = m;
    __syncthreads();
    float M = fmaxf(fmaxf(sm->red[0], sm->red[1]),
                    fmaxf(sm->red[2], sm->red[3]));
    __syncthreads();
    float sum = 0.f;
    for (int i = tid; i < 8016; i += 256) {
      float4 v = sc4[i];
      sum += expf(v.x - M) + expf(v.y - M) + expf(v.z - M) + expf(v.w - M);
    }
#pragma unroll
    for (int off = 32; off; off >>= 1) sum += __shfl_xor(sum, off);
    if (lane == 0) sm->red[wave] = sum;
    __syncthreads();
    float logZ = M + logf(sm->red[0] + sm->red[1] + sm->red[2] + sm->red[3]);
    if (tid < 64) {
      sm->s_src[tid] = sources[tid];
      sm->s_pc[tid]  = ws[WS_SC + tid] - logZ;
    }
    __syncthreads();
    int v = bid * 256 + tid;                  // 125*256 = 32000 exactly
    float acc = ws[WS_SG + v] - logZ;
#pragma unroll
    for (int i = 0; i < S; ++i) acc += (sm->s_src[i] == v) ? sm->s_pc[i] : 0.f;
    st1<B>(d_out, v, acc);
  }
}

__launch_bounds__(256, 2)
__global__ void k_all(const int* word_input, const void* prev_context,
                      const void* ph, const void* enc, const int* sources,
                      const int* targets, const int* ti, const int* utf,
                      const void* emb_table, const void* Wih, const void* Whh,
                      const void* bih, const void* bhh, const void* copy_W,
                      const void* copy_b, const void* gen_W, const void* gen_b,
                      float* ws, void* d_out) {
  __shared__ Sm sm;
  __shared__ int s_flag;
  int tid = threadIdx.x;
  // per-block dtype detection on gen_W (deterministic, all blocks agree ->
  // all blocks take the same templated path -> barriers are uniform)
  if (tid < 64) {
    const ushort_t* g = (const ushort_t*)gen_W;
    int cnt = 0;
#pragma unroll
    for (int k = 0; k < 4; ++k) {
      float a = fabsf(b2f(g[2 * (tid + 64 * k)]));
      if (a >= 1e-5f && a <= 1.0f) ++cnt;
    }
#pragma unroll
    for (int off = 32; off; off >>= 1) cnt += __shfl_down(cnt, off);
    if (tid == 0) s_flag = (cnt >= 128) ? 1 : 0;
  }
  if (tid == 65) sm.s_di = utf[0] ? targets[ti[0]] : word_input[0];
  __syncthreads();
  int FB = s_flag;
  int di = sm.s_di;
  if (FB) body<true >(word_input, prev_context, ph, enc, sources, emb_table,
                      Wih, Whh, bih, bhh, copy_W, copy_b, gen_W, gen_b,
                      ws, d_out, &sm, di);
  else    body<false>(word_input, prev_context, ph, enc, sources, emb_table,
                      Wih, Whh, bih, bhh, copy_W, copy_b, gen_W, gen_b,
                      ws, d_out, &sm, di);
}

extern "C" void kernel_launch(void* const* d_in, const int* in_sizes, int n_in,
                              void* d_out, int out_size, void* d_ws, size_t ws_size,
                              hipStream_t stream) {
  const int*  word_input   = (const int*)d_in[0];
  const void* prev_context = d_in[1];
  const void* prev_hidden  = d_in[2];
  const void* enc          = d_in[3];
  const int*  sources      = (const int*)d_in[4];
  const int*  targets      = (const int*)d_in[5];
  const int*  ti           = (const int*)d_in[6];
  const int*  utf          = (const int*)d_in[7];
  const void* emb_table    = d_in[8];
  const void* gru_Wih      = d_in[9];
  const void* gru_Whh      = d_in[10];
  const void* gru_bih      = d_in[11];
  const void* gru_bhh      = d_in[12];
  const void* copy_W       = d_in[13];
  const void* copy_b       = d_in[14];
  const void* gen_W        = d_in[15];
  const void* gen_b        = d_in[16];
  float* ws = (float*)d_ws;

  // zero the grid-barrier counters (ws is poisoned between runs);
  // hipMemsetAsync is stream-ordered and graph-capturable.
  hipMemsetAsync(ws, 0, 64, stream);

  // 512 blocks x 256 threads: __launch_bounds__(256,2) caps VGPR<=256 ->
  // 2 waves/SIMD -> 2 blocks/CU; LDS 26.4KB*2 < 160KB -> all 512 blocks
  // co-resident on 256 CUs, so the ws-based grid barrier cannot deadlock.
  k_all<<<NBLK, 256, 0, stream>>>(word_input, prev_context, prev_hidden, enc,
                                  sources, targets, ti, utf, emb_table,
                                  gru_Wih, gru_Whh, gru_bih, gru_bhh,
                                  copy_W, copy_b, gen_W, gen_b, ws, d_out);
}